// Round 7
// baseline (230.045 us; speedup 1.0000x reference)
//
#include <hip/hip_runtime.h>
#include <hip/hip_fp16.h>

#define N_NODES 16384
#define N_EDGES 131072
#define DB 2048
#define DF 512
#define FP8_SCALE 16.0f
#define FP8_DESCALE (1.0f / 256.0f)
#define SPREAD 16                                   // ints between counters (64B cacheline)

// ---- workspace layout (float-unit offsets) ----
#define WS_STATS   0                                // 64 x 5 partials
#define WS_PAR     320                              // 256
#define WS_PBF     576                              // N packed (pb,pf) fp16
#define WS_DEGB    (WS_PBF + N_NODES)
#define WS_DEGF    (WS_DEGB + N_NODES)
#define WS_ACC     (WS_DEGF + N_NODES)              // p0 + C per node
#define WS_STARTB  (WS_ACC + N_NODES)               // N+4 ints (excl prefix, [N]=E)
#define WS_STARTF  (WS_STARTB + N_NODES + 4)
#define WS_HISTB   (WS_STARTF + N_NODES + 4)        // N*SPREAD ints: hist then cursors
#define WS_HISTF   (WS_HISTB + N_NODES * SPREAD)
#define WS_EDGEB   (WS_HISTF + N_NODES * SPREAD)    // E words: src | (sim_fp16 << 16), dst-sorted
#define WS_EDGEF   (WS_EDGEB + N_EDGES)
#define WS_FNB     (WS_EDGEF + N_EDGES)             // N*DB fp8
#define WS_FNF     (WS_FNB + N_NODES * DB / 4)      // N*DF fp8

typedef float fv2 __attribute__((ext_vector_type(2)));

#if __has_builtin(__builtin_amdgcn_cvt_pk_f32_fp8) && __has_builtin(__builtin_amdgcn_cvt_pk_fp8_f32)
#define HAS_FP8HW 1
#else
#define HAS_FP8HW 0
#endif

// ---- fp16 helpers ----
__device__ __forceinline__ uint32_t pack_h2(float x, float y) {
    union { __half2 h; uint32_t u; } c; c.h = __floats2half2_rn(x, y); return c.u;
}
__device__ __forceinline__ uint16_t f2h_bits(float f) {
    union { __half h; uint16_t u; } c; c.h = __float2half_rn(f); return c.u;
}
__device__ __forceinline__ float h_bits2f(uint16_t u) {
    union { uint16_t u; __half h; } c; c.u = u; return __half2float(c.h);
}

// ---- fp8 e4m3 helpers ----
#if !HAS_FP8HW
__device__ __forceinline__ float fp8d_soft(uint32_t b) {
    uint32_t s = (b >> 7) & 1u, e = (b >> 3) & 0xFu, m = b & 7u;
    float v = (e == 0) ? (float)m * 0.001953125f
                       : (1.0f + (float)m * 0.125f) * exp2f((float)((int)e - 7));
    return s ? -v : v;
}
__device__ __forceinline__ uint32_t fp8e_soft(float f) {
    uint32_t s = (__float_as_uint(f) >> 31) << 7;
    float a = fabsf(f);
    if (a < 0.015625f) {
        int m = (int)rintf(a * 512.0f);
        if (m > 7) return s | (1u << 3);
        return s | (uint32_t)m;
    }
    uint32_t u = __float_as_uint(a);
    uint32_t r = u + 0x000FFFFFu + ((u >> 20) & 1u);
    int e8 = (int)(r >> 23) - 127 + 7;
    if (e8 >= 16) return s | (15u << 3) | 6u;
    return s | ((uint32_t)e8 << 3) | ((r >> 20) & 7u);
}
#endif

__device__ __forceinline__ float u32dot(uint32_t u, const float* s, float acc) {
#if HAS_FP8HW
    fv2 lo = __builtin_amdgcn_cvt_pk_f32_fp8(u, false);
    fv2 hi = __builtin_amdgcn_cvt_pk_f32_fp8(u, true);
    acc += s[0] * lo.x; acc += s[1] * lo.y;
    acc += s[2] * hi.x; acc += s[3] * hi.y;
#else
    acc += s[0] * fp8d_soft(u & 0xFF);
    acc += s[1] * fp8d_soft((u >> 8) & 0xFF);
    acc += s[2] * fp8d_soft((u >> 16) & 0xFF);
    acc += s[3] * fp8d_soft((u >> 24) & 0xFF);
#endif
    return acc;
}
__device__ __forceinline__ void u32cvt(uint32_t u, float* d) {
#if HAS_FP8HW
    fv2 lo = __builtin_amdgcn_cvt_pk_f32_fp8(u, false);
    fv2 hi = __builtin_amdgcn_cvt_pk_f32_fp8(u, true);
    d[0] = lo.x; d[1] = lo.y; d[2] = hi.x; d[3] = hi.y;
#else
    d[0] = fp8d_soft(u & 0xFF); d[1] = fp8d_soft((u >> 8) & 0xFF);
    d[2] = fp8d_soft((u >> 16) & 0xFF); d[3] = fp8d_soft((u >> 24) & 0xFF);
#endif
}
__device__ __forceinline__ uint32_t pack4_fp8(float a, float b, float c, float d) {
#if HAS_FP8HW
    uint32_t u = 0;
    u = __builtin_amdgcn_cvt_pk_fp8_f32(a, b, u, false);
    u = __builtin_amdgcn_cvt_pk_fp8_f32(c, d, u, true);
    return u;
#else
    return fp8e_soft(a) | (fp8e_soft(b) << 8) | (fp8e_soft(c) << 16) | (fp8e_soft(d) << 24);
#endif
}
__device__ __forceinline__ float dot16_fp8(uint4 r, const float* s, float acc) {
    acc = u32dot(r.x, s + 0, acc);  acc = u32dot(r.y, s + 4, acc);
    acc = u32dot(r.z, s + 8, acc);  acc = u32dot(r.w, s + 12, acc);
    return acc;
}

// ---- launch 1: stats (0..63) + deg init (64..191) + hist zero (192..2239) ----
__global__ void k_pre(const float* __restrict__ x, float* __restrict__ ws) {
    if (blockIdx.x < 64) {
        float s0 = 0.f, s1 = 0.f, s2 = 0.f, s3 = 0.f, s4 = 0.f;
        for (int i = blockIdx.x * 256 + threadIdx.x; i < N_NODES; i += 64 * 256) {
            float2 v = ((const float2*)x)[i];
            s0 += v.x; s1 += v.y;
            s2 += v.x * v.x; s3 += v.y * v.y; s4 += v.x * v.y;
        }
        #pragma unroll
        for (int off = 32; off; off >>= 1) {
            s0 += __shfl_down(s0, off); s1 += __shfl_down(s1, off);
            s2 += __shfl_down(s2, off); s3 += __shfl_down(s3, off);
            s4 += __shfl_down(s4, off);
        }
        __shared__ float red[4][5];
        int w = threadIdx.x >> 6;
        if ((threadIdx.x & 63) == 0) {
            red[w][0] = s0; red[w][1] = s1; red[w][2] = s2; red[w][3] = s3; red[w][4] = s4;
        }
        __syncthreads();
        if (threadIdx.x < 5) {
            ws[WS_STATS + blockIdx.x * 5 + threadIdx.x] =
                red[0][threadIdx.x] + red[1][threadIdx.x] +
                red[2][threadIdx.x] + red[3][threadIdx.x];
        }
    } else if (blockIdx.x < 192) {
        int j = (blockIdx.x - 64) * 256 + threadIdx.x;   // [0, 32768)
        ws[WS_DEGB + j] = 1.f;                           // DEGB then DEGF (contiguous 2N)
    } else {
        int j = (blockIdx.x - 192) * 256 + threadIdx.x;  // [0, 2*N*SPREAD)
        ((int*)(ws + WS_HISTB))[j] = 0;
    }
}

// ---- launch 2: in-degree histogram (by DST) into spread counters ----
__global__ void k_hist(const int* __restrict__ eib, const int* __restrict__ eif,
                       float* __restrict__ ws) {
    int e = blockIdx.x * blockDim.x + threadIdx.x;
    if (e < N_EDGES) {
        atomicAdd(&((int*)(ws + WS_HISTB))[eib[N_EDGES + e] * SPREAD], 1);
    } else {
        int e2 = e - N_EDGES;
        atomicAdd(&((int*)(ws + WS_HISTF))[eif[N_EDGES + e2] * SPREAD], 1);
    }
}

// ---- launch 3: block 0 = prefix scan (spread hist -> compact start + spread cursors);
//               block 1 = closed-form params ----
__global__ void k_scan(const float* __restrict__ w1, const float* __restrict__ b1,
                       const float* __restrict__ gamma, const float* __restrict__ beta,
                       const float* __restrict__ w2, const float* __restrict__ b2,
                       const float* __restrict__ w0w, const float* __restrict__ w0b,
                       const float* __restrict__ gbw, const float* __restrict__ gbb,
                       const float* __restrict__ gfw, const float* __restrict__ gfb,
                       const float* __restrict__ wbw, const float* __restrict__ wbb,
                       const float* __restrict__ wfw, const float* __restrict__ wfb,
                       float* __restrict__ ws) {
    if (blockIdx.x == 0) {
        __shared__ int wsum[4];
        int t = threadIdx.x;
        int lane = t & 63, w = t >> 6;
        for (int g = 0; g < 2; g++) {
            int* hist = (int*)(ws + (g ? WS_HISTF : WS_HISTB));
            int* st   = (int*)(ws + (g ? WS_STARTF : WS_STARTB));
            int base = t * 64;
            int csum = 0;
            for (int j = 0; j < 64; j++) csum += hist[(base + j) * SPREAD];
            int v = csum;
            #pragma unroll
            for (int off = 1; off < 64; off <<= 1) {
                int n = __shfl_up(v, off);
                if (lane >= off) v += n;
            }
            if (lane == 63) wsum[w] = v;
            __syncthreads();
            int add = 0;
            for (int k = 0; k < w; k++) add += wsum[k];
            int run = v + add - csum;         // exclusive prefix of this chunk
            for (int j = 0; j < 64; j++) {
                int c = hist[(base + j) * SPREAD];
                st[base + j] = run;
                hist[(base + j) * SPREAD] = run;   // cursor init (in place)
                run += c;
            }
            if (t == 255) st[N_NODES] = run;
            __syncthreads();
        }
    } else {
        __shared__ float st5[5];
        if (threadIdx.x < 5) {
            float t = 0.f;
            for (int b = 0; b < 64; b++) t += ws[WS_STATS + b * 5 + threadIdx.x];
            st5[threadIdx.x] = t;
        }
        __syncthreads();
        const float inv_n = 1.0f / (float)N_NODES;
        float m0 = st5[0] * inv_n, m1 = st5[1] * inv_n;
        float v0 = st5[2] * inv_n - m0 * m0;
        float v1 = st5[3] * inv_n - m1 * m1;
        float cv = st5[4] * inv_n - m0 * m1;
        float* par = ws + WS_PAR;
        int j = threadIdx.x;
        if (j < 32) {
            float W0 = w1[j], W1 = w1[32 + j];
            float mu  = m0 * W0 + m1 * W1 + b1[j];
            float var = W0 * W0 * v0 + W1 * W1 * v1 + 2.f * W0 * W1 * cv;
            float is  = rsqrtf(var + 1e-5f) * gamma[j];
            par[j]      = W0 * is;
            par[32 + j] = W1 * is;
            par[64 + j] = (b1[j] - mu) * is + beta[j];
            float u0 = 0.f, ub = 0.f, uf = 0.f;
            for (int k = 0; k < 32; k++) {
                float w2jk = w2[j * 32 + k];
                float vbk = 0.f, vfk = 0.f;
                for (int n = 0; n < 32; n++) {
                    vbk += gbw[k * 32 + n] * wbw[n];
                    vfk += gfw[k * 32 + n] * wfw[n];
                }
                u0 += w2jk * w0w[k];
                ub += w2jk * vbk;
                uf += w2jk * vfk;
            }
            par[96 + j]  = u0;
            par[128 + j] = ub;
            par[160 + j] = uf;
        }
        if (threadIdx.x == 0) {
            float C = w0b[0] + wbb[0] + wfb[0];
            float pc0 = 0.f, pcb = 0.f, pcf = 0.f;
            for (int k = 0; k < 32; k++) {
                float vbk = 0.f, vfk = 0.f;
                for (int n = 0; n < 32; n++) {
                    vbk += gbw[k * 32 + n] * wbw[n];
                    vfk += gfw[k * 32 + n] * wfw[n];
                }
                pc0 += b2[k] * w0w[k];
                pcb += b2[k] * vbk;
                pcf += b2[k] * vfk;
                C   += gbb[k] * wbw[k] + gfb[k] * wfw[k];
            }
            par[192] = C; par[193] = pc0; par[194] = pcb; par[195] = pcf;
        }
    }
}

// ---- launch 4: counting-sort scatter (spread cursors) ----
__global__ void k_sortscatter(const int* __restrict__ eib, const int* __restrict__ eif,
                              float* __restrict__ ws) {
    int e = blockIdx.x * blockDim.x + threadIdx.x;
    if (e < N_EDGES) {
        int s = eib[e], d = eib[N_EDGES + e];
        int pos = atomicAdd(&((int*)(ws + WS_HISTB))[d * SPREAD], 1);
        ((uint32_t*)(ws + WS_EDGEB))[pos] = (uint32_t)s;
    } else {
        int e2 = e - N_EDGES;
        int s = eif[e2], d = eif[N_EDGES + e2];
        int pos = atomicAdd(&((int*)(ws + WS_HISTF))[d * SPREAD], 1);
        ((uint32_t*)(ws + WS_EDGEF))[pos] = (uint32_t)s;
    }
}

// ---- launch 5: per-node scalars ----
__global__ void k_nodes(const float* __restrict__ x, const float* __restrict__ prelu_a,
                        float* __restrict__ ws) {
    int i = blockIdx.x * blockDim.x + threadIdx.x;
    if (i >= N_NODES) return;
    const float* par = ws + WS_PAR;
    float alpha = prelu_a[0];
    float2 v = ((const float2*)x)[i];
    float p0 = par[193], pb = par[194], pf = par[195];
    #pragma unroll
    for (int j = 0; j < 32; j++) {
        float z = v.x * par[j] + v.y * par[32 + j] + par[64 + j];
        float h = z > 0.f ? z : alpha * z;
        p0 += h * par[96 + j];
        pb += h * par[128 + j];
        pf += h * par[160 + j];
    }
    ws[WS_ACC + i] = p0 + par[192];
    ((uint32_t*)(ws + WS_PBF))[i] = pack_h2(pb, pf);
}

// ---- launch 6: normalize -> fp8. body block-per-row (0..16383), face wave-per-row (16384..20479) ----
__global__ void k_norm(const float* __restrict__ bfeat, const float* __restrict__ ffeat,
                       float* __restrict__ ws) {
    __shared__ float red[4];
    int b = blockIdx.x;
    if (b < N_NODES) {
        int t = threadIdx.x;
        const float4* F = (const float4*)bfeat + (size_t)b * (DB / 4);
        float4 a0 = F[2 * t];
        float4 a1 = F[2 * t + 1];
        float aa = a0.x * a0.x + a0.y * a0.y + a0.z * a0.z + a0.w * a0.w
                 + a1.x * a1.x + a1.y * a1.y + a1.z * a1.z + a1.w * a1.w;
        #pragma unroll
        for (int off = 32; off; off >>= 1) aa += __shfl_xor(aa, off);
        if ((t & 63) == 0) red[t >> 6] = aa;
        __syncthreads();
        float tot = red[0] + red[1] + red[2] + red[3];
        float inv = rsqrtf(tot + 1e-12f) * FP8_SCALE;
        uint2 o;
        o.x = pack4_fp8(a0.x * inv, a0.y * inv, a0.z * inv, a0.w * inv);
        o.y = pack4_fp8(a1.x * inv, a1.y * inv, a1.z * inv, a1.w * inv);
        ((uint2*)(ws + WS_FNB))[(size_t)b * 256 + t] = o;
    } else {
        int idx = (b - N_NODES) * 4 + (threadIdx.x >> 6);
        int lane = threadIdx.x & 63;
        if (idx >= N_NODES) return;
        const float4* F = (const float4*)ffeat + (size_t)idx * (DF / 4);
        float4 a0 = F[2 * lane];
        float4 a1 = F[2 * lane + 1];
        float aa = a0.x * a0.x + a0.y * a0.y + a0.z * a0.z + a0.w * a0.w
                 + a1.x * a1.x + a1.y * a1.y + a1.z * a1.z + a1.w * a1.w;
        #pragma unroll
        for (int off = 32; off; off >>= 1) aa += __shfl_xor(aa, off);
        float inv = rsqrtf(aa + 1e-12f) * FP8_SCALE;
        uint2 o;
        o.x = pack4_fp8(a0.x * inv, a0.y * inv, a0.z * inv, a0.w * inv);
        o.y = pack4_fp8(a1.x * inv, a1.y * inv, a1.z * inv, a1.w * inv);
        ((uint2*)(ws + WS_FNF))[(size_t)idx * 64 + lane] = o;
    }
}

// ---- launch 7: one wave per DST node; dst row in regs; gather src rows ----
__global__ void k_edge_all(float* __restrict__ ws) {
    int wid  = (int)((blockIdx.x * blockDim.x + threadIdx.x) >> 6);
    int lane = threadIdx.x & 63;
    if (wid < N_NODES) {
        const int* start = (const int*)(ws + WS_STARTB);
        uint32_t* edges  = (uint32_t*)(ws + WS_EDGEB);
        int st = start[wid], en = start[wid + 1];
        if (st >= en) return;
        const uint4* fn = (const uint4*)(ws + WS_FNB);
        const uint4* Dp = fn + (size_t)wid * 128;
        uint4 r0 = Dp[lane], r1 = Dp[lane + 64];
        float dstf[32];
        u32cvt(r0.x, dstf + 0);  u32cvt(r0.y, dstf + 4);
        u32cvt(r0.z, dstf + 8);  u32cvt(r0.w, dstf + 12);
        u32cvt(r1.x, dstf + 16); u32cvt(r1.y, dstf + 20);
        u32cvt(r1.z, dstf + 24); u32cvt(r1.w, dstf + 28);
        float wdeg = 0.f;
        int i = st;
        for (; i + 3 < en; i += 4) {
            uint32_t w0 = edges[i], w1 = edges[i + 1], w2 = edges[i + 2], w3 = edges[i + 3];
            const uint4* A = fn + (size_t)(w0 & 0xFFFFu) * 128;
            const uint4* B = fn + (size_t)(w1 & 0xFFFFu) * 128;
            const uint4* C = fn + (size_t)(w2 & 0xFFFFu) * 128;
            const uint4* E = fn + (size_t)(w3 & 0xFFFFu) * 128;
            uint4 a0 = A[lane], a1 = A[lane + 64];
            uint4 b0 = B[lane], b1 = B[lane + 64];
            uint4 c0 = C[lane], c1 = C[lane + 64];
            uint4 e0 = E[lane], e1 = E[lane + 64];
            float s0 = 0.f, s1 = 0.f, s2 = 0.f, s3 = 0.f;
            s0 = dot16_fp8(a0, dstf, s0); s0 = dot16_fp8(a1, dstf + 16, s0);
            s1 = dot16_fp8(b0, dstf, s1); s1 = dot16_fp8(b1, dstf + 16, s1);
            s2 = dot16_fp8(c0, dstf, s2); s2 = dot16_fp8(c1, dstf + 16, s2);
            s3 = dot16_fp8(e0, dstf, s3); s3 = dot16_fp8(e1, dstf + 16, s3);
            #pragma unroll
            for (int off = 32; off; off >>= 1) {
                s0 += __shfl_xor(s0, off); s1 += __shfl_xor(s1, off);
                s2 += __shfl_xor(s2, off); s3 += __shfl_xor(s3, off);
            }
            if (lane == 0) {
                float m0 = fmaxf(s0, 0.f) * FP8_DESCALE;
                float m1 = fmaxf(s1, 0.f) * FP8_DESCALE;
                float m2 = fmaxf(s2, 0.f) * FP8_DESCALE;
                float m3 = fmaxf(s3, 0.f) * FP8_DESCALE;
                edges[i]     = (w0 & 0xFFFFu) | ((uint32_t)f2h_bits(m0) << 16);
                edges[i + 1] = (w1 & 0xFFFFu) | ((uint32_t)f2h_bits(m1) << 16);
                edges[i + 2] = (w2 & 0xFFFFu) | ((uint32_t)f2h_bits(m2) << 16);
                edges[i + 3] = (w3 & 0xFFFFu) | ((uint32_t)f2h_bits(m3) << 16);
                wdeg += m0 + m1 + m2 + m3;
            }
        }
        for (; i < en; i++) {
            uint32_t w0 = edges[i];
            const uint4* A = fn + (size_t)(w0 & 0xFFFFu) * 128;
            uint4 a0 = A[lane], a1 = A[lane + 64];
            float s0 = 0.f;
            s0 = dot16_fp8(a0, dstf, s0); s0 = dot16_fp8(a1, dstf + 16, s0);
            #pragma unroll
            for (int off = 32; off; off >>= 1) s0 += __shfl_xor(s0, off);
            if (lane == 0) {
                float m0 = fmaxf(s0, 0.f) * FP8_DESCALE;
                edges[i] = (w0 & 0xFFFFu) | ((uint32_t)f2h_bits(m0) << 16);
                wdeg += m0;
            }
        }
        if (lane == 0) ws[WS_DEGB + wid] = 1.f + wdeg;
    } else {
        int nid = wid - N_NODES;
        if (nid >= N_NODES) return;
        const int* start = (const int*)(ws + WS_STARTF);
        uint32_t* edges  = (uint32_t*)(ws + WS_EDGEF);
        int st = start[nid], en = start[nid + 1];
        if (st >= en) return;
        const uint2* fn = (const uint2*)(ws + WS_FNF);
        uint2 sv = fn[(size_t)nid * 64 + lane];
        float dstf[8];
        u32cvt(sv.x, dstf); u32cvt(sv.y, dstf + 4);
        float wdeg = 0.f;
        int i = st;
        for (; i + 3 < en; i += 4) {
            uint32_t w0 = edges[i], w1 = edges[i + 1], w2 = edges[i + 2], w3 = edges[i + 3];
            uint2 r0 = fn[(size_t)(w0 & 0xFFFFu) * 64 + lane];
            uint2 r1 = fn[(size_t)(w1 & 0xFFFFu) * 64 + lane];
            uint2 r2 = fn[(size_t)(w2 & 0xFFFFu) * 64 + lane];
            uint2 r3 = fn[(size_t)(w3 & 0xFFFFu) * 64 + lane];
            float c0 = u32dot(r0.y, dstf + 4, u32dot(r0.x, dstf, 0.f));
            float c1 = u32dot(r1.y, dstf + 4, u32dot(r1.x, dstf, 0.f));
            float c2 = u32dot(r2.y, dstf + 4, u32dot(r2.x, dstf, 0.f));
            float c3 = u32dot(r3.y, dstf + 4, u32dot(r3.x, dstf, 0.f));
            #pragma unroll
            for (int off = 32; off; off >>= 1) {
                c0 += __shfl_xor(c0, off); c1 += __shfl_xor(c1, off);
                c2 += __shfl_xor(c2, off); c3 += __shfl_xor(c3, off);
            }
            if (lane == 0) {
                float m0 = fmaxf(c0, 0.f) * FP8_DESCALE;
                float m1 = fmaxf(c1, 0.f) * FP8_DESCALE;
                float m2 = fmaxf(c2, 0.f) * FP8_DESCALE;
                float m3 = fmaxf(c3, 0.f) * FP8_DESCALE;
                edges[i]     = (w0 & 0xFFFFu) | ((uint32_t)f2h_bits(m0) << 16);
                edges[i + 1] = (w1 & 0xFFFFu) | ((uint32_t)f2h_bits(m1) << 16);
                edges[i + 2] = (w2 & 0xFFFFu) | ((uint32_t)f2h_bits(m2) << 16);
                edges[i + 3] = (w3 & 0xFFFFu) | ((uint32_t)f2h_bits(m3) << 16);
                wdeg += m0 + m1 + m2 + m3;
            }
        }
        for (; i < en; i++) {
            uint32_t w0 = edges[i];
            uint2 r0 = fn[(size_t)(w0 & 0xFFFFu) * 64 + lane];
            float c0 = u32dot(r0.y, dstf + 4, u32dot(r0.x, dstf, 0.f));
            #pragma unroll
            for (int off = 32; off; off >>= 1) c0 += __shfl_xor(c0, off);
            if (lane == 0) {
                float m0 = fmaxf(c0, 0.f) * FP8_DESCALE;
                edges[i] = (w0 & 0xFFFFu) | ((uint32_t)f2h_bits(m0) << 16);
                wdeg += m0;
            }
        }
        if (lane == 0) ws[WS_DEGF + nid] = 1.f + wdeg;
    }
}

// ---- launch 8: thread-per-(dst,graph) pull; graph-1 partial joins via LDS ----
__global__ void k_out(float* __restrict__ out, const float* __restrict__ ws) {
    __shared__ float part[128];
    int half = threadIdx.x >> 7;              // wave-uniform (waves 0,1 vs 2,3)
    int li   = threadIdx.x & 127;
    int i    = blockIdx.x * 128 + li;
    const uint32_t* pk = (const uint32_t*)(ws + WS_PBF);
    int g = half;
    const int* st       = (const int*)(ws + (g ? WS_STARTF : WS_STARTB));
    const uint32_t* eg  = (const uint32_t*)(ws + (g ? WS_EDGEF : WS_EDGEB));
    const float* deg    = ws + (g ? WS_DEGF : WS_DEGB);
    float sum = 0.f;
    int e0 = st[i], e1 = st[i + 1];
    for (int e = e0; e < e1; e++) {
        uint32_t w = eg[e];
        float sm = h_bits2f((uint16_t)(w >> 16));
        if (sm > 0.f) {
            int s = (int)(w & 0xFFFFu);
            uint32_t ps = pk[s];
            float p = h_bits2f(g ? (uint16_t)(ps >> 16) : (uint16_t)(ps & 0xFFFFu));
            sum += rsqrtf(fmaxf(deg[s], 1e-6f)) * sm * p;
        }
    }
    float dn = rsqrtf(fmaxf(deg[i], 1e-6f));
    uint32_t pme = pk[i];
    float pv = h_bits2f(g ? (uint16_t)(pme >> 16) : (uint16_t)(pme & 0xFFFFu));
    float contrib = dn * (dn * pv + sum);
    if (half == 1) part[li] = contrib;
    __syncthreads();
    if (half == 0) out[i] = ws[WS_ACC + i] + contrib + part[li];
}

extern "C" void kernel_launch(void* const* d_in, const int* in_sizes, int n_in,
                              void* d_out, int out_size, void* d_ws, size_t ws_size,
                              hipStream_t stream) {
    const float* x     = (const float*)d_in[0];
    const float* bfeat = (const float*)d_in[1];
    const float* ffeat = (const float*)d_in[2];
    const int*   eib   = (const int*)d_in[3];
    const int*   eif   = (const int*)d_in[4];
    const float* w1    = (const float*)d_in[5];
    const float* b1    = (const float*)d_in[6];
    const float* gam   = (const float*)d_in[7];
    const float* bet   = (const float*)d_in[8];
    const float* pa    = (const float*)d_in[9];
    const float* w2    = (const float*)d_in[10];
    const float* b2    = (const float*)d_in[11];
    const float* w0w   = (const float*)d_in[12];
    const float* w0b   = (const float*)d_in[13];
    const float* gbw   = (const float*)d_in[14];
    const float* gbb   = (const float*)d_in[15];
    const float* gfw   = (const float*)d_in[16];
    const float* gfb   = (const float*)d_in[17];
    const float* wbw   = (const float*)d_in[18];
    const float* wbb   = (const float*)d_in[19];
    const float* wfw   = (const float*)d_in[20];
    const float* wfb   = (const float*)d_in[21];

    float* ws  = (float*)d_ws;
    float* out = (float*)d_out;

    k_pre<<<dim3(2240), dim3(256), 0, stream>>>(x, ws);
    k_hist<<<dim3(1024), dim3(256), 0, stream>>>(eib, eif, ws);
    k_scan<<<dim3(2), dim3(256), 0, stream>>>(w1, b1, gam, bet, w2, b2, w0w, w0b,
                                              gbw, gbb, gfw, gfb, wbw, wbb, wfw, wfb, ws);
    k_sortscatter<<<dim3(1024), dim3(256), 0, stream>>>(eib, eif, ws);
    k_nodes<<<dim3(N_NODES / 256), dim3(256), 0, stream>>>(x, pa, ws);
    k_norm<<<dim3(N_NODES + N_NODES / 4), dim3(256), 0, stream>>>(bfeat, ffeat, ws);
    k_edge_all<<<dim3(2 * N_NODES / 4), dim3(256), 0, stream>>>(ws);
    k_out<<<dim3(N_NODES / 128), dim3(256), 0, stream>>>(out, ws);
}

// Round 8
// 172.656 us; speedup vs baseline: 1.3324x; 1.3324x over previous
//
#include <hip/hip_runtime.h>
#include <hip/hip_fp16.h>

#define N_NODES 16384
#define N_EDGES 131072
#define DB 2048
#define DF 512
#define FP8_SCALE 16.0f
#define FP8_DESCALE (1.0f / 256.0f)
#define SPREAD 16                                   // ints between counters (64B cacheline)

// ---- workspace layout (float-unit offsets) ----
#define WS_STATS   0                                // 64 x 5 partials
#define WS_PAR     320                              // 256
#define WS_PBF     576                              // N packed (pb,pf) fp16
#define WS_DEGB    (WS_PBF + N_NODES)
#define WS_DEGF    (WS_DEGB + N_NODES)
#define WS_ACC     (WS_DEGF + N_NODES)              // p0 + C per node
#define WS_STARTB  (WS_ACC + N_NODES)               // N+4 ints (excl prefix, [N]=E)
#define WS_STARTF  (WS_STARTB + N_NODES + 4)
#define WS_HISTB   (WS_STARTF + N_NODES + 4)        // N*SPREAD ints: hist then cursors
#define WS_HISTF   (WS_HISTB + N_NODES * SPREAD)
#define WS_EDGEB   (WS_HISTF + N_NODES * SPREAD)    // E words: src | (sim_fp16 << 16), dst-sorted
#define WS_EDGEF   (WS_EDGEB + N_EDGES)
#define WS_FNB     (WS_EDGEF + N_EDGES)             // N*DB fp8
#define WS_FNF     (WS_FNB + N_NODES * DB / 4)      // N*DF fp8
#define WS_BSUM    (WS_FNF + N_NODES * DF / 4)      // 128 ints block sums

typedef float fv2 __attribute__((ext_vector_type(2)));

#if __has_builtin(__builtin_amdgcn_cvt_pk_f32_fp8) && __has_builtin(__builtin_amdgcn_cvt_pk_fp8_f32)
#define HAS_FP8HW 1
#else
#define HAS_FP8HW 0
#endif

// ---- fp16 helpers ----
__device__ __forceinline__ uint32_t pack_h2(float x, float y) {
    union { __half2 h; uint32_t u; } c; c.h = __floats2half2_rn(x, y); return c.u;
}
__device__ __forceinline__ uint16_t f2h_bits(float f) {
    union { __half h; uint16_t u; } c; c.h = __float2half_rn(f); return c.u;
}
__device__ __forceinline__ float h_bits2f(uint16_t u) {
    union { uint16_t u; __half h; } c; c.u = u; return __half2float(c.h);
}

// ---- fp8 e4m3 helpers ----
#if !HAS_FP8HW
__device__ __forceinline__ float fp8d_soft(uint32_t b) {
    uint32_t s = (b >> 7) & 1u, e = (b >> 3) & 0xFu, m = b & 7u;
    float v = (e == 0) ? (float)m * 0.001953125f
                       : (1.0f + (float)m * 0.125f) * exp2f((float)((int)e - 7));
    return s ? -v : v;
}
__device__ __forceinline__ uint32_t fp8e_soft(float f) {
    uint32_t s = (__float_as_uint(f) >> 31) << 7;
    float a = fabsf(f);
    if (a < 0.015625f) {
        int m = (int)rintf(a * 512.0f);
        if (m > 7) return s | (1u << 3);
        return s | (uint32_t)m;
    }
    uint32_t u = __float_as_uint(a);
    uint32_t r = u + 0x000FFFFFu + ((u >> 20) & 1u);
    int e8 = (int)(r >> 23) - 127 + 7;
    if (e8 >= 16) return s | (15u << 3) | 6u;
    return s | ((uint32_t)e8 << 3) | ((r >> 20) & 7u);
}
#endif

__device__ __forceinline__ float u32dot(uint32_t u, const float* s, float acc) {
#if HAS_FP8HW
    fv2 lo = __builtin_amdgcn_cvt_pk_f32_fp8(u, false);
    fv2 hi = __builtin_amdgcn_cvt_pk_f32_fp8(u, true);
    acc += s[0] * lo.x; acc += s[1] * lo.y;
    acc += s[2] * hi.x; acc += s[3] * hi.y;
#else
    acc += s[0] * fp8d_soft(u & 0xFF);
    acc += s[1] * fp8d_soft((u >> 8) & 0xFF);
    acc += s[2] * fp8d_soft((u >> 16) & 0xFF);
    acc += s[3] * fp8d_soft((u >> 24) & 0xFF);
#endif
    return acc;
}
__device__ __forceinline__ void u32cvt(uint32_t u, float* d) {
#if HAS_FP8HW
    fv2 lo = __builtin_amdgcn_cvt_pk_f32_fp8(u, false);
    fv2 hi = __builtin_amdgcn_cvt_pk_f32_fp8(u, true);
    d[0] = lo.x; d[1] = lo.y; d[2] = hi.x; d[3] = hi.y;
#else
    d[0] = fp8d_soft(u & 0xFF); d[1] = fp8d_soft((u >> 8) & 0xFF);
    d[2] = fp8d_soft((u >> 16) & 0xFF); d[3] = fp8d_soft((u >> 24) & 0xFF);
#endif
}
__device__ __forceinline__ uint32_t pack4_fp8(float a, float b, float c, float d) {
#if HAS_FP8HW
    uint32_t u = 0;
    u = __builtin_amdgcn_cvt_pk_fp8_f32(a, b, u, false);
    u = __builtin_amdgcn_cvt_pk_fp8_f32(c, d, u, true);
    return u;
#else
    return fp8e_soft(a) | (fp8e_soft(b) << 8) | (fp8e_soft(c) << 16) | (fp8e_soft(d) << 24);
#endif
}
__device__ __forceinline__ float dot16_fp8(uint4 r, const float* s, float acc) {
    acc = u32dot(r.x, s + 0, acc);  acc = u32dot(r.y, s + 4, acc);
    acc = u32dot(r.z, s + 8, acc);  acc = u32dot(r.w, s + 12, acc);
    return acc;
}

// ---- launch 1: stats (0..63) + deg init (64..191) + hist zero (192..2239) ----
__global__ void k_pre(const float* __restrict__ x, float* __restrict__ ws) {
    if (blockIdx.x < 64) {
        float s0 = 0.f, s1 = 0.f, s2 = 0.f, s3 = 0.f, s4 = 0.f;
        for (int i = blockIdx.x * 256 + threadIdx.x; i < N_NODES; i += 64 * 256) {
            float2 v = ((const float2*)x)[i];
            s0 += v.x; s1 += v.y;
            s2 += v.x * v.x; s3 += v.y * v.y; s4 += v.x * v.y;
        }
        #pragma unroll
        for (int off = 32; off; off >>= 1) {
            s0 += __shfl_down(s0, off); s1 += __shfl_down(s1, off);
            s2 += __shfl_down(s2, off); s3 += __shfl_down(s3, off);
            s4 += __shfl_down(s4, off);
        }
        __shared__ float red[4][5];
        int w = threadIdx.x >> 6;
        if ((threadIdx.x & 63) == 0) {
            red[w][0] = s0; red[w][1] = s1; red[w][2] = s2; red[w][3] = s3; red[w][4] = s4;
        }
        __syncthreads();
        if (threadIdx.x < 5) {
            ws[WS_STATS + blockIdx.x * 5 + threadIdx.x] =
                red[0][threadIdx.x] + red[1][threadIdx.x] +
                red[2][threadIdx.x] + red[3][threadIdx.x];
        }
    } else if (blockIdx.x < 192) {
        int j = (blockIdx.x - 64) * 256 + threadIdx.x;   // [0, 32768)
        ws[WS_DEGB + j] = 1.f;                           // DEGB then DEGF (contiguous 2N)
    } else {
        int j = (blockIdx.x - 192) * 256 + threadIdx.x;  // [0, 2*N*SPREAD)
        ((int*)(ws + WS_HISTB))[j] = 0;
    }
}

// ---- launch 2: in-degree histogram (by DST) into spread counters ----
__global__ void k_hist(const int* __restrict__ eib, const int* __restrict__ eif,
                       float* __restrict__ ws) {
    int e = blockIdx.x * blockDim.x + threadIdx.x;
    if (e < N_EDGES) {
        atomicAdd(&((int*)(ws + WS_HISTB))[eib[N_EDGES + e] * SPREAD], 1);
    } else {
        int e2 = e - N_EDGES;
        atomicAdd(&((int*)(ws + WS_HISTF))[eif[N_EDGES + e2] * SPREAD], 1);
    }
}

// ---- launch 3: scan phase A (blocks 0..127: per-block sums) + normalize (128+) ----
__global__ void k_scanA(const float* __restrict__ bfeat, const float* __restrict__ ffeat,
                        float* __restrict__ ws) {
    __shared__ float redf[4];
    __shared__ int redi[4];
    int b = blockIdx.x;
    if (b < 128) {
        int g = b >> 6;
        int idx = (b & 63) * 256 + threadIdx.x;
        const int* hist = (const int*)(ws + (g ? WS_HISTF : WS_HISTB));
        int v = hist[idx * SPREAD];
        #pragma unroll
        for (int off = 32; off; off >>= 1) v += __shfl_xor(v, off);
        if ((threadIdx.x & 63) == 0) redi[threadIdx.x >> 6] = v;
        __syncthreads();
        if (threadIdx.x == 0)
            ((int*)(ws + WS_BSUM))[b] = redi[0] + redi[1] + redi[2] + redi[3];
    } else if (b < 128 + N_NODES) {
        int row = b - 128;
        int t = threadIdx.x;
        const float4* F = (const float4*)bfeat + (size_t)row * (DB / 4);
        float4 a0 = F[2 * t];
        float4 a1 = F[2 * t + 1];
        float aa = a0.x * a0.x + a0.y * a0.y + a0.z * a0.z + a0.w * a0.w
                 + a1.x * a1.x + a1.y * a1.y + a1.z * a1.z + a1.w * a1.w;
        #pragma unroll
        for (int off = 32; off; off >>= 1) aa += __shfl_xor(aa, off);
        if ((t & 63) == 0) redf[t >> 6] = aa;
        __syncthreads();
        float tot = redf[0] + redf[1] + redf[2] + redf[3];
        float inv = rsqrtf(tot + 1e-12f) * FP8_SCALE;
        uint2 o;
        o.x = pack4_fp8(a0.x * inv, a0.y * inv, a0.z * inv, a0.w * inv);
        o.y = pack4_fp8(a1.x * inv, a1.y * inv, a1.z * inv, a1.w * inv);
        ((uint2*)(ws + WS_FNB))[(size_t)row * 256 + t] = o;
    } else {
        int idx = (b - 128 - N_NODES) * 4 + (threadIdx.x >> 6);
        int lane = threadIdx.x & 63;
        if (idx >= N_NODES) return;
        const float4* F = (const float4*)ffeat + (size_t)idx * (DF / 4);
        float4 a0 = F[2 * lane];
        float4 a1 = F[2 * lane + 1];
        float aa = a0.x * a0.x + a0.y * a0.y + a0.z * a0.z + a0.w * a0.w
                 + a1.x * a1.x + a1.y * a1.y + a1.z * a1.z + a1.w * a1.w;
        #pragma unroll
        for (int off = 32; off; off >>= 1) aa += __shfl_xor(aa, off);
        float inv = rsqrtf(aa + 1e-12f) * FP8_SCALE;
        uint2 o;
        o.x = pack4_fp8(a0.x * inv, a0.y * inv, a0.z * inv, a0.w * inv);
        o.y = pack4_fp8(a1.x * inv, a1.y * inv, a1.z * inv, a1.w * inv);
        ((uint2*)(ws + WS_FNF))[(size_t)idx * 64 + lane] = o;
    }
}

// ---- launch 4: scan phase B (block 0: scan 128 block sums) + params (block 1) ----
__global__ void k_scanB(const float* __restrict__ w1, const float* __restrict__ b1,
                        const float* __restrict__ gamma, const float* __restrict__ beta,
                        const float* __restrict__ w2, const float* __restrict__ b2,
                        const float* __restrict__ w0w, const float* __restrict__ w0b,
                        const float* __restrict__ gbw, const float* __restrict__ gbb,
                        const float* __restrict__ gfw, const float* __restrict__ gfb,
                        const float* __restrict__ wbw, const float* __restrict__ wbb,
                        const float* __restrict__ wfw, const float* __restrict__ wfb,
                        float* __restrict__ ws) {
    if (blockIdx.x == 0) {
        int t = threadIdx.x;
        if (t < 128) {
            int* bs = (int*)(ws + WS_BSUM);
            int lane = t & 63;                  // two 64-wide groups = two waves
            int v = bs[t];
            int s = v;
            #pragma unroll
            for (int off = 1; off < 64; off <<= 1) {
                int n = __shfl_up(s, off);
                if (lane >= off) s += n;
            }
            bs[t] = s - v;                       // exclusive within graph
        }
        if (t == 0) {
            ((int*)(ws + WS_STARTB))[N_NODES] = N_EDGES;
            ((int*)(ws + WS_STARTF))[N_NODES] = N_EDGES;
        }
    } else {
        __shared__ float st5[5];
        if (threadIdx.x < 5) {
            float t = 0.f;
            for (int b = 0; b < 64; b++) t += ws[WS_STATS + b * 5 + threadIdx.x];
            st5[threadIdx.x] = t;
        }
        __syncthreads();
        const float inv_n = 1.0f / (float)N_NODES;
        float m0 = st5[0] * inv_n, m1 = st5[1] * inv_n;
        float v0 = st5[2] * inv_n - m0 * m0;
        float v1 = st5[3] * inv_n - m1 * m1;
        float cv = st5[4] * inv_n - m0 * m1;
        float* par = ws + WS_PAR;
        int j = threadIdx.x;
        if (j < 32) {
            float W0 = w1[j], W1 = w1[32 + j];
            float mu  = m0 * W0 + m1 * W1 + b1[j];
            float var = W0 * W0 * v0 + W1 * W1 * v1 + 2.f * W0 * W1 * cv;
            float is  = rsqrtf(var + 1e-5f) * gamma[j];
            par[j]      = W0 * is;
            par[32 + j] = W1 * is;
            par[64 + j] = (b1[j] - mu) * is + beta[j];
            float u0 = 0.f, ub = 0.f, uf = 0.f;
            for (int k = 0; k < 32; k++) {
                float w2jk = w2[j * 32 + k];
                float vbk = 0.f, vfk = 0.f;
                for (int n = 0; n < 32; n++) {
                    vbk += gbw[k * 32 + n] * wbw[n];
                    vfk += gfw[k * 32 + n] * wfw[n];
                }
                u0 += w2jk * w0w[k];
                ub += w2jk * vbk;
                uf += w2jk * vfk;
            }
            par[96 + j]  = u0;
            par[128 + j] = ub;
            par[160 + j] = uf;
        }
        if (threadIdx.x == 0) {
            float C = w0b[0] + wbb[0] + wfb[0];
            float pc0 = 0.f, pcb = 0.f, pcf = 0.f;
            for (int k = 0; k < 32; k++) {
                float vbk = 0.f, vfk = 0.f;
                for (int n = 0; n < 32; n++) {
                    vbk += gbw[k * 32 + n] * wbw[n];
                    vfk += gfw[k * 32 + n] * wfw[n];
                }
                pc0 += b2[k] * w0w[k];
                pcb += b2[k] * vbk;
                pcf += b2[k] * vfk;
                C   += gbb[k] * wbw[k] + gfb[k] * wfw[k];
            }
            par[192] = C; par[193] = pc0; par[194] = pcb; par[195] = pcf;
        }
    }
}

// ---- launch 5: scan phase C (blocks 0..127: per-counter exclusive prefix) + nodes (128..191) ----
__global__ void k_scanC(const float* __restrict__ x, const float* __restrict__ prelu_a,
                        float* __restrict__ ws) {
    __shared__ int wsum[4];
    int b = blockIdx.x;
    if (b < 128) {
        int g = b >> 6;
        int idx = (b & 63) * 256 + threadIdx.x;
        int* hist = (int*)(ws + (g ? WS_HISTF : WS_HISTB));
        int* st   = (int*)(ws + (g ? WS_STARTF : WS_STARTB));
        int lane = threadIdx.x & 63, w = threadIdx.x >> 6;
        int c = hist[idx * SPREAD];
        int s = c;
        #pragma unroll
        for (int off = 1; off < 64; off <<= 1) {
            int n = __shfl_up(s, off);
            if (lane >= off) s += n;
        }
        if (lane == 63) wsum[w] = s;
        __syncthreads();
        int add = ((const int*)(ws + WS_BSUM))[b];
        for (int k = 0; k < w; k++) add += wsum[k];
        int excl = s - c + add;
        st[idx] = excl;
        hist[idx * SPREAD] = excl;               // cursor init
    } else {
        int i = (b - 128) * 256 + threadIdx.x;
        if (i >= N_NODES) return;
        const float* par = ws + WS_PAR;
        float alpha = prelu_a[0];
        float2 v = ((const float2*)x)[i];
        float p0 = par[193], pb = par[194], pf = par[195];
        #pragma unroll
        for (int j = 0; j < 32; j++) {
            float z = v.x * par[j] + v.y * par[32 + j] + par[64 + j];
            float h = z > 0.f ? z : alpha * z;
            p0 += h * par[96 + j];
            pb += h * par[128 + j];
            pf += h * par[160 + j];
        }
        ws[WS_ACC + i] = p0 + par[192];
        ((uint32_t*)(ws + WS_PBF))[i] = pack_h2(pb, pf);
    }
}

// ---- launch 6: counting-sort scatter (spread cursors) ----
__global__ void k_sortscatter(const int* __restrict__ eib, const int* __restrict__ eif,
                              float* __restrict__ ws) {
    int e = blockIdx.x * blockDim.x + threadIdx.x;
    if (e < N_EDGES) {
        int s = eib[e], d = eib[N_EDGES + e];
        int pos = atomicAdd(&((int*)(ws + WS_HISTB))[d * SPREAD], 1);
        ((uint32_t*)(ws + WS_EDGEB))[pos] = (uint32_t)s;
    } else {
        int e2 = e - N_EDGES;
        int s = eif[e2], d = eif[N_EDGES + e2];
        int pos = atomicAdd(&((int*)(ws + WS_HISTF))[d * SPREAD], 1);
        ((uint32_t*)(ws + WS_EDGEF))[pos] = (uint32_t)s;
    }
}

// ---- launch 7: one wave per DST node; dst row in regs; gather src rows ----
__global__ void k_edge_all(float* __restrict__ ws) {
    int wid  = (int)((blockIdx.x * blockDim.x + threadIdx.x) >> 6);
    int lane = threadIdx.x & 63;
    if (wid < N_NODES) {
        const int* start = (const int*)(ws + WS_STARTB);
        uint32_t* edges  = (uint32_t*)(ws + WS_EDGEB);
        int st = start[wid], en = start[wid + 1];
        if (st >= en) return;
        const uint4* fn = (const uint4*)(ws + WS_FNB);
        const uint4* Dp = fn + (size_t)wid * 128;
        uint4 r0 = Dp[lane], r1 = Dp[lane + 64];
        float dstf[32];
        u32cvt(r0.x, dstf + 0);  u32cvt(r0.y, dstf + 4);
        u32cvt(r0.z, dstf + 8);  u32cvt(r0.w, dstf + 12);
        u32cvt(r1.x, dstf + 16); u32cvt(r1.y, dstf + 20);
        u32cvt(r1.z, dstf + 24); u32cvt(r1.w, dstf + 28);
        float wdeg = 0.f;
        int i = st;
        for (; i + 3 < en; i += 4) {
            uint32_t w0 = edges[i], w1 = edges[i + 1], w2 = edges[i + 2], w3 = edges[i + 3];
            const uint4* A = fn + (size_t)(w0 & 0xFFFFu) * 128;
            const uint4* B = fn + (size_t)(w1 & 0xFFFFu) * 128;
            const uint4* C = fn + (size_t)(w2 & 0xFFFFu) * 128;
            const uint4* E = fn + (size_t)(w3 & 0xFFFFu) * 128;
            uint4 a0 = A[lane], a1 = A[lane + 64];
            uint4 b0 = B[lane], b1 = B[lane + 64];
            uint4 c0 = C[lane], c1 = C[lane + 64];
            uint4 e0 = E[lane], e1 = E[lane + 64];
            float s0 = 0.f, s1 = 0.f, s2 = 0.f, s3 = 0.f;
            s0 = dot16_fp8(a0, dstf, s0); s0 = dot16_fp8(a1, dstf + 16, s0);
            s1 = dot16_fp8(b0, dstf, s1); s1 = dot16_fp8(b1, dstf + 16, s1);
            s2 = dot16_fp8(c0, dstf, s2); s2 = dot16_fp8(c1, dstf + 16, s2);
            s3 = dot16_fp8(e0, dstf, s3); s3 = dot16_fp8(e1, dstf + 16, s3);
            #pragma unroll
            for (int off = 32; off; off >>= 1) {
                s0 += __shfl_xor(s0, off); s1 += __shfl_xor(s1, off);
                s2 += __shfl_xor(s2, off); s3 += __shfl_xor(s3, off);
            }
            if (lane == 0) {
                float m0 = fmaxf(s0, 0.f) * FP8_DESCALE;
                float m1 = fmaxf(s1, 0.f) * FP8_DESCALE;
                float m2 = fmaxf(s2, 0.f) * FP8_DESCALE;
                float m3 = fmaxf(s3, 0.f) * FP8_DESCALE;
                edges[i]     = (w0 & 0xFFFFu) | ((uint32_t)f2h_bits(m0) << 16);
                edges[i + 1] = (w1 & 0xFFFFu) | ((uint32_t)f2h_bits(m1) << 16);
                edges[i + 2] = (w2 & 0xFFFFu) | ((uint32_t)f2h_bits(m2) << 16);
                edges[i + 3] = (w3 & 0xFFFFu) | ((uint32_t)f2h_bits(m3) << 16);
                wdeg += m0 + m1 + m2 + m3;
            }
        }
        for (; i < en; i++) {
            uint32_t w0 = edges[i];
            const uint4* A = fn + (size_t)(w0 & 0xFFFFu) * 128;
            uint4 a0 = A[lane], a1 = A[lane + 64];
            float s0 = 0.f;
            s0 = dot16_fp8(a0, dstf, s0); s0 = dot16_fp8(a1, dstf + 16, s0);
            #pragma unroll
            for (int off = 32; off; off >>= 1) s0 += __shfl_xor(s0, off);
            if (lane == 0) {
                float m0 = fmaxf(s0, 0.f) * FP8_DESCALE;
                edges[i] = (w0 & 0xFFFFu) | ((uint32_t)f2h_bits(m0) << 16);
                wdeg += m0;
            }
        }
        if (lane == 0) ws[WS_DEGB + wid] = 1.f + wdeg;
    } else {
        int nid = wid - N_NODES;
        if (nid >= N_NODES) return;
        const int* start = (const int*)(ws + WS_STARTF);
        uint32_t* edges  = (uint32_t*)(ws + WS_EDGEF);
        int st = start[nid], en = start[nid + 1];
        if (st >= en) return;
        const uint2* fn = (const uint2*)(ws + WS_FNF);
        uint2 sv = fn[(size_t)nid * 64 + lane];
        float dstf[8];
        u32cvt(sv.x, dstf); u32cvt(sv.y, dstf + 4);
        float wdeg = 0.f;
        int i = st;
        for (; i + 3 < en; i += 4) {
            uint32_t w0 = edges[i], w1 = edges[i + 1], w2 = edges[i + 2], w3 = edges[i + 3];
            uint2 r0 = fn[(size_t)(w0 & 0xFFFFu) * 64 + lane];
            uint2 r1 = fn[(size_t)(w1 & 0xFFFFu) * 64 + lane];
            uint2 r2 = fn[(size_t)(w2 & 0xFFFFu) * 64 + lane];
            uint2 r3 = fn[(size_t)(w3 & 0xFFFFu) * 64 + lane];
            float c0 = u32dot(r0.y, dstf + 4, u32dot(r0.x, dstf, 0.f));
            float c1 = u32dot(r1.y, dstf + 4, u32dot(r1.x, dstf, 0.f));
            float c2 = u32dot(r2.y, dstf + 4, u32dot(r2.x, dstf, 0.f));
            float c3 = u32dot(r3.y, dstf + 4, u32dot(r3.x, dstf, 0.f));
            #pragma unroll
            for (int off = 32; off; off >>= 1) {
                c0 += __shfl_xor(c0, off); c1 += __shfl_xor(c1, off);
                c2 += __shfl_xor(c2, off); c3 += __shfl_xor(c3, off);
            }
            if (lane == 0) {
                float m0 = fmaxf(c0, 0.f) * FP8_DESCALE;
                float m1 = fmaxf(c1, 0.f) * FP8_DESCALE;
                float m2 = fmaxf(c2, 0.f) * FP8_DESCALE;
                float m3 = fmaxf(c3, 0.f) * FP8_DESCALE;
                edges[i]     = (w0 & 0xFFFFu) | ((uint32_t)f2h_bits(m0) << 16);
                edges[i + 1] = (w1 & 0xFFFFu) | ((uint32_t)f2h_bits(m1) << 16);
                edges[i + 2] = (w2 & 0xFFFFu) | ((uint32_t)f2h_bits(m2) << 16);
                edges[i + 3] = (w3 & 0xFFFFu) | ((uint32_t)f2h_bits(m3) << 16);
                wdeg += m0 + m1 + m2 + m3;
            }
        }
        for (; i < en; i++) {
            uint32_t w0 = edges[i];
            uint2 r0 = fn[(size_t)(w0 & 0xFFFFu) * 64 + lane];
            float c0 = u32dot(r0.y, dstf + 4, u32dot(r0.x, dstf, 0.f));
            #pragma unroll
            for (int off = 32; off; off >>= 1) c0 += __shfl_xor(c0, off);
            if (lane == 0) {
                float m0 = fmaxf(c0, 0.f) * FP8_DESCALE;
                edges[i] = (w0 & 0xFFFFu) | ((uint32_t)f2h_bits(m0) << 16);
                wdeg += m0;
            }
        }
        if (lane == 0) ws[WS_DEGF + nid] = 1.f + wdeg;
    }
}

// ---- launch 8: thread-per-(dst,graph) pull; graph-1 partial joins via LDS ----
__global__ void k_out(float* __restrict__ out, const float* __restrict__ ws) {
    __shared__ float part[128];
    int half = threadIdx.x >> 7;              // wave-uniform (waves 0,1 vs 2,3)
    int li   = threadIdx.x & 127;
    int i    = blockIdx.x * 128 + li;
    const uint32_t* pk = (const uint32_t*)(ws + WS_PBF);
    int g = half;
    const int* st       = (const int*)(ws + (g ? WS_STARTF : WS_STARTB));
    const uint32_t* eg  = (const uint32_t*)(ws + (g ? WS_EDGEF : WS_EDGEB));
    const float* deg    = ws + (g ? WS_DEGF : WS_DEGB);
    float sum = 0.f;
    int e0 = st[i], e1 = st[i + 1];
    for (int e = e0; e < e1; e++) {
        uint32_t w = eg[e];
        float sm = h_bits2f((uint16_t)(w >> 16));
        if (sm > 0.f) {
            int s = (int)(w & 0xFFFFu);
            uint32_t ps = pk[s];
            float p = h_bits2f(g ? (uint16_t)(ps >> 16) : (uint16_t)(ps & 0xFFFFu));
            sum += rsqrtf(fmaxf(deg[s], 1e-6f)) * sm * p;
        }
    }
    float dn = rsqrtf(fmaxf(deg[i], 1e-6f));
    uint32_t pme = pk[i];
    float pv = h_bits2f(g ? (uint16_t)(pme >> 16) : (uint16_t)(pme & 0xFFFFu));
    float contrib = dn * (dn * pv + sum);
    if (half == 1) part[li] = contrib;
    __syncthreads();
    if (half == 0) out[i] = ws[WS_ACC + i] + contrib + part[li];
}

extern "C" void kernel_launch(void* const* d_in, const int* in_sizes, int n_in,
                              void* d_out, int out_size, void* d_ws, size_t ws_size,
                              hipStream_t stream) {
    const float* x     = (const float*)d_in[0];
    const float* bfeat = (const float*)d_in[1];
    const float* ffeat = (const float*)d_in[2];
    const int*   eib   = (const int*)d_in[3];
    const int*   eif   = (const int*)d_in[4];
    const float* w1    = (const float*)d_in[5];
    const float* b1    = (const float*)d_in[6];
    const float* gam   = (const float*)d_in[7];
    const float* bet   = (const float*)d_in[8];
    const float* pa    = (const float*)d_in[9];
    const float* w2    = (const float*)d_in[10];
    const float* b2    = (const float*)d_in[11];
    const float* w0w   = (const float*)d_in[12];
    const float* w0b   = (const float*)d_in[13];
    const float* gbw   = (const float*)d_in[14];
    const float* gbb   = (const float*)d_in[15];
    const float* gfw   = (const float*)d_in[16];
    const float* gfb   = (const float*)d_in[17];
    const float* wbw   = (const float*)d_in[18];
    const float* wbb   = (const float*)d_in[19];
    const float* wfw   = (const float*)d_in[20];
    const float* wfb   = (const float*)d_in[21];

    float* ws  = (float*)d_ws;
    float* out = (float*)d_out;

    k_pre<<<dim3(2240), dim3(256), 0, stream>>>(x, ws);
    k_hist<<<dim3(1024), dim3(256), 0, stream>>>(eib, eif, ws);
    k_scanA<<<dim3(128 + N_NODES + N_NODES / 4), dim3(256), 0, stream>>>(bfeat, ffeat, ws);
    k_scanB<<<dim3(2), dim3(256), 0, stream>>>(w1, b1, gam, bet, w2, b2, w0w, w0b,
                                               gbw, gbb, gfw, gfb, wbw, wbb, wfw, wfb, ws);
    k_scanC<<<dim3(192), dim3(256), 0, stream>>>(x, pa, ws);
    k_sortscatter<<<dim3(1024), dim3(256), 0, stream>>>(eib, eif, ws);
    k_edge_all<<<dim3(2 * N_NODES / 4), dim3(256), 0, stream>>>(ws);
    k_out<<<dim3(N_NODES / 128), dim3(256), 0, stream>>>(out, ws);
}

// Round 9
// 172.227 us; speedup vs baseline: 1.3357x; 1.0025x over previous
//
#include <hip/hip_runtime.h>
#include <hip/hip_fp16.h>

#define N_NODES 16384
#define N_EDGES 131072
#define DB 2048
#define DF 512
#define FP8_SCALE 16.0f
#define FP8_DESCALE (1.0f / 256.0f)
#define SPREAD 16                                   // ints between counters (64B cacheline)

// ---- workspace layout (float-unit offsets) ----
#define WS_STATS   0                                // 64 x 5 partials
#define WS_PAR     320                              // 256
#define WS_PBF     576                              // N packed (pb,pf) fp16
#define WS_DNB     (WS_PBF + N_NODES)               // N: dn = rsqrt(deg) body
#define WS_DNF     (WS_DNB + N_NODES)
#define WS_WQB     (WS_DNF + N_NODES)               // N: dn*p body
#define WS_WQF     (WS_WQB + N_NODES)
#define WS_ACC     (WS_WQF + N_NODES)               // p0 + C per node
#define WS_STARTB  (WS_ACC + N_NODES)               // N+4 ints (excl prefix, [N]=E)
#define WS_STARTF  (WS_STARTB + N_NODES + 4)
#define WS_HISTB   (WS_STARTF + N_NODES + 4)        // N*SPREAD ints: hist then cursors
#define WS_HISTF   (WS_HISTB + N_NODES * SPREAD)
#define WS_EDGEB   (WS_HISTF + N_NODES * SPREAD)    // E words: src | (sim_fp16 << 16), dst-sorted
#define WS_EDGEF   (WS_EDGEB + N_EDGES)
#define WS_FNB     (WS_EDGEF + N_EDGES)             // N*DB fp8
#define WS_FNF     (WS_FNB + N_NODES * DB / 4)      // N*DF fp8
#define WS_BSUM    (WS_FNF + N_NODES * DF / 4)      // 128 ints block sums

typedef float fv2 __attribute__((ext_vector_type(2)));

#if __has_builtin(__builtin_amdgcn_cvt_pk_f32_fp8) && __has_builtin(__builtin_amdgcn_cvt_pk_fp8_f32)
#define HAS_FP8HW 1
#else
#define HAS_FP8HW 0
#endif

// ---- fp16 helpers ----
__device__ __forceinline__ uint32_t pack_h2(float x, float y) {
    union { __half2 h; uint32_t u; } c; c.h = __floats2half2_rn(x, y); return c.u;
}
__device__ __forceinline__ uint16_t f2h_bits(float f) {
    union { __half h; uint16_t u; } c; c.h = __float2half_rn(f); return c.u;
}
__device__ __forceinline__ float h_bits2f(uint16_t u) {
    union { uint16_t u; __half h; } c; c.u = u; return __half2float(c.h);
}

// ---- fp8 e4m3 helpers ----
#if !HAS_FP8HW
__device__ __forceinline__ float fp8d_soft(uint32_t b) {
    uint32_t s = (b >> 7) & 1u, e = (b >> 3) & 0xFu, m = b & 7u;
    float v = (e == 0) ? (float)m * 0.001953125f
                       : (1.0f + (float)m * 0.125f) * exp2f((float)((int)e - 7));
    return s ? -v : v;
}
__device__ __forceinline__ uint32_t fp8e_soft(float f) {
    uint32_t s = (__float_as_uint(f) >> 31) << 7;
    float a = fabsf(f);
    if (a < 0.015625f) {
        int m = (int)rintf(a * 512.0f);
        if (m > 7) return s | (1u << 3);
        return s | (uint32_t)m;
    }
    uint32_t u = __float_as_uint(a);
    uint32_t r = u + 0x000FFFFFu + ((u >> 20) & 1u);
    int e8 = (int)(r >> 23) - 127 + 7;
    if (e8 >= 16) return s | (15u << 3) | 6u;
    return s | ((uint32_t)e8 << 3) | ((r >> 20) & 7u);
}
#endif

__device__ __forceinline__ float u32dot(uint32_t u, const float* s, float acc) {
#if HAS_FP8HW
    fv2 lo = __builtin_amdgcn_cvt_pk_f32_fp8(u, false);
    fv2 hi = __builtin_amdgcn_cvt_pk_f32_fp8(u, true);
    acc += s[0] * lo.x; acc += s[1] * lo.y;
    acc += s[2] * hi.x; acc += s[3] * hi.y;
#else
    acc += s[0] * fp8d_soft(u & 0xFF);
    acc += s[1] * fp8d_soft((u >> 8) & 0xFF);
    acc += s[2] * fp8d_soft((u >> 16) & 0xFF);
    acc += s[3] * fp8d_soft((u >> 24) & 0xFF);
#endif
    return acc;
}
__device__ __forceinline__ void u32cvt(uint32_t u, float* d) {
#if HAS_FP8HW
    fv2 lo = __builtin_amdgcn_cvt_pk_f32_fp8(u, false);
    fv2 hi = __builtin_amdgcn_cvt_pk_f32_fp8(u, true);
    d[0] = lo.x; d[1] = lo.y; d[2] = hi.x; d[3] = hi.y;
#else
    d[0] = fp8d_soft(u & 0xFF); d[1] = fp8d_soft((u >> 8) & 0xFF);
    d[2] = fp8d_soft((u >> 16) & 0xFF); d[3] = fp8d_soft((u >> 24) & 0xFF);
#endif
}
__device__ __forceinline__ uint32_t pack4_fp8(float a, float b, float c, float d) {
#if HAS_FP8HW
    uint32_t u = 0;
    u = __builtin_amdgcn_cvt_pk_fp8_f32(a, b, u, false);
    u = __builtin_amdgcn_cvt_pk_fp8_f32(c, d, u, true);
    return u;
#else
    return fp8e_soft(a) | (fp8e_soft(b) << 8) | (fp8e_soft(c) << 16) | (fp8e_soft(d) << 24);
#endif
}
__device__ __forceinline__ float dot16_fp8(uint4 r, const float* s, float acc) {
    acc = u32dot(r.x, s + 0, acc);  acc = u32dot(r.y, s + 4, acc);
    acc = u32dot(r.z, s + 8, acc);  acc = u32dot(r.w, s + 12, acc);
    return acc;
}

// ---- launch 1: stats (0..63) + hist zero (64..2111) ----
__global__ void k_pre(const float* __restrict__ x, float* __restrict__ ws) {
    if (blockIdx.x < 64) {
        float s0 = 0.f, s1 = 0.f, s2 = 0.f, s3 = 0.f, s4 = 0.f;
        for (int i = blockIdx.x * 256 + threadIdx.x; i < N_NODES; i += 64 * 256) {
            float2 v = ((const float2*)x)[i];
            s0 += v.x; s1 += v.y;
            s2 += v.x * v.x; s3 += v.y * v.y; s4 += v.x * v.y;
        }
        #pragma unroll
        for (int off = 32; off; off >>= 1) {
            s0 += __shfl_down(s0, off); s1 += __shfl_down(s1, off);
            s2 += __shfl_down(s2, off); s3 += __shfl_down(s3, off);
            s4 += __shfl_down(s4, off);
        }
        __shared__ float red[4][5];
        int w = threadIdx.x >> 6;
        if ((threadIdx.x & 63) == 0) {
            red[w][0] = s0; red[w][1] = s1; red[w][2] = s2; red[w][3] = s3; red[w][4] = s4;
        }
        __syncthreads();
        if (threadIdx.x < 5) {
            ws[WS_STATS + blockIdx.x * 5 + threadIdx.x] =
                red[0][threadIdx.x] + red[1][threadIdx.x] +
                red[2][threadIdx.x] + red[3][threadIdx.x];
        }
    } else {
        int j = (blockIdx.x - 64) * 256 + threadIdx.x;  // [0, 2*N*SPREAD)
        ((int*)(ws + WS_HISTB))[j] = 0;
    }
}

// ---- launch 2: in-degree histogram (by DST) into spread counters ----
__global__ void k_hist(const int* __restrict__ eib, const int* __restrict__ eif,
                       float* __restrict__ ws) {
    int e = blockIdx.x * blockDim.x + threadIdx.x;
    if (e < N_EDGES) {
        atomicAdd(&((int*)(ws + WS_HISTB))[eib[N_EDGES + e] * SPREAD], 1);
    } else {
        int e2 = e - N_EDGES;
        atomicAdd(&((int*)(ws + WS_HISTF))[eif[N_EDGES + e2] * SPREAD], 1);
    }
}

// ---- launch 3: scan phase A (blocks 0..127: per-block sums) + params (block 128) ----
__global__ void k_scanA(const float* __restrict__ w1, const float* __restrict__ b1,
                        const float* __restrict__ gamma, const float* __restrict__ beta,
                        const float* __restrict__ w2, const float* __restrict__ b2,
                        const float* __restrict__ w0w, const float* __restrict__ w0b,
                        const float* __restrict__ gbw, const float* __restrict__ gbb,
                        const float* __restrict__ gfw, const float* __restrict__ gfb,
                        const float* __restrict__ wbw, const float* __restrict__ wbb,
                        const float* __restrict__ wfw, const float* __restrict__ wfb,
                        float* __restrict__ ws) {
    int b = blockIdx.x;
    if (b < 128) {
        __shared__ int redi[4];
        int g = b >> 6;
        int idx = (b & 63) * 256 + threadIdx.x;
        const int* hist = (const int*)(ws + (g ? WS_HISTF : WS_HISTB));
        int v = hist[idx * SPREAD];
        #pragma unroll
        for (int off = 32; off; off >>= 1) v += __shfl_xor(v, off);
        if ((threadIdx.x & 63) == 0) redi[threadIdx.x >> 6] = v;
        __syncthreads();
        if (threadIdx.x == 0)
            ((int*)(ws + WS_BSUM))[b] = redi[0] + redi[1] + redi[2] + redi[3];
    } else {
        __shared__ float st5[5];
        if (threadIdx.x < 5) {
            float t = 0.f;
            for (int k = 0; k < 64; k++) t += ws[WS_STATS + k * 5 + threadIdx.x];
            st5[threadIdx.x] = t;
        }
        __syncthreads();
        const float inv_n = 1.0f / (float)N_NODES;
        float m0 = st5[0] * inv_n, m1 = st5[1] * inv_n;
        float v0 = st5[2] * inv_n - m0 * m0;
        float v1 = st5[3] * inv_n - m1 * m1;
        float cv = st5[4] * inv_n - m0 * m1;
        float* par = ws + WS_PAR;
        int j = threadIdx.x;
        if (j < 32) {
            float W0 = w1[j], W1 = w1[32 + j];
            float mu  = m0 * W0 + m1 * W1 + b1[j];
            float var = W0 * W0 * v0 + W1 * W1 * v1 + 2.f * W0 * W1 * cv;
            float is  = rsqrtf(var + 1e-5f) * gamma[j];
            par[j]      = W0 * is;
            par[32 + j] = W1 * is;
            par[64 + j] = (b1[j] - mu) * is + beta[j];
            float u0 = 0.f, ub = 0.f, uf = 0.f;
            for (int k = 0; k < 32; k++) {
                float w2jk = w2[j * 32 + k];
                float vbk = 0.f, vfk = 0.f;
                for (int n = 0; n < 32; n++) {
                    vbk += gbw[k * 32 + n] * wbw[n];
                    vfk += gfw[k * 32 + n] * wfw[n];
                }
                u0 += w2jk * w0w[k];
                ub += w2jk * vbk;
                uf += w2jk * vfk;
            }
            par[96 + j]  = u0;
            par[128 + j] = ub;
            par[160 + j] = uf;
        }
        if (threadIdx.x == 0) {
            float C = w0b[0] + wbb[0] + wfb[0];
            float pc0 = 0.f, pcb = 0.f, pcf = 0.f;
            for (int k = 0; k < 32; k++) {
                float vbk = 0.f, vfk = 0.f;
                for (int n = 0; n < 32; n++) {
                    vbk += gbw[k * 32 + n] * wbw[n];
                    vfk += gfw[k * 32 + n] * wfw[n];
                }
                pc0 += b2[k] * w0w[k];
                pcb += b2[k] * vbk;
                pcf += b2[k] * vfk;
                C   += gbb[k] * wbw[k] + gfb[k] * wfw[k];
            }
            par[192] = C; par[193] = pc0; par[194] = pcb; par[195] = pcf;
        }
    }
}

// ---- launch 4: scan phase B — 1 block scans 128 block sums (per-graph exclusive) ----
__global__ void k_scanB(float* __restrict__ ws) {
    int t = threadIdx.x;
    if (t < 128) {
        int* bs = (int*)(ws + WS_BSUM);
        int lane = t & 63;                   // wave0 = graph B, wave1 = graph F
        int v = bs[t];
        int s = v;
        #pragma unroll
        for (int off = 1; off < 64; off <<= 1) {
            int n = __shfl_up(s, off);
            if (lane >= off) s += n;
        }
        bs[t] = s - v;                       // exclusive within graph
    }
    if (t == 0) {
        ((int*)(ws + WS_STARTB))[N_NODES] = N_EDGES;
        ((int*)(ws + WS_STARTF))[N_NODES] = N_EDGES;
    }
}

// ---- launch 5: scan phase C (0..127: per-counter exclusive prefix) + nodes (128..191) ----
__global__ void k_scanC(const float* __restrict__ x, const float* __restrict__ prelu_a,
                        float* __restrict__ ws) {
    __shared__ int wsum[4];
    int b = blockIdx.x;
    if (b < 128) {
        int g = b >> 6;
        int idx = (b & 63) * 256 + threadIdx.x;
        int* hist = (int*)(ws + (g ? WS_HISTF : WS_HISTB));
        int* st   = (int*)(ws + (g ? WS_STARTF : WS_STARTB));
        int lane = threadIdx.x & 63, w = threadIdx.x >> 6;
        int c = hist[idx * SPREAD];
        int s = c;
        #pragma unroll
        for (int off = 1; off < 64; off <<= 1) {
            int n = __shfl_up(s, off);
            if (lane >= off) s += n;
        }
        if (lane == 63) wsum[w] = s;
        __syncthreads();
        int add = ((const int*)(ws + WS_BSUM))[b];
        for (int k = 0; k < w; k++) add += wsum[k];
        int excl = s - c + add;
        st[idx] = excl;
        hist[idx * SPREAD] = excl;               // cursor init
    } else {
        int i = (b - 128) * 256 + threadIdx.x;
        if (i >= N_NODES) return;
        const float* par = ws + WS_PAR;
        float alpha = prelu_a[0];
        float2 v = ((const float2*)x)[i];
        float p0 = par[193], pb = par[194], pf = par[195];
        #pragma unroll
        for (int j = 0; j < 32; j++) {
            float z = v.x * par[j] + v.y * par[32 + j] + par[64 + j];
            float h = z > 0.f ? z : alpha * z;
            p0 += h * par[96 + j];
            pb += h * par[128 + j];
            pf += h * par[160 + j];
        }
        ws[WS_ACC + i] = p0 + par[192];
        ((uint32_t*)(ws + WS_PBF))[i] = pack_h2(pb, pf);
    }
}

// ---- launch 6: sortscatter (0..1023) + body norm (1024..17407) + face norm (17408..21503) ----
__global__ void k_sortnorm(const int* __restrict__ eib, const int* __restrict__ eif,
                           const float* __restrict__ bfeat, const float* __restrict__ ffeat,
                           float* __restrict__ ws) {
    __shared__ float redf[4];
    int b = blockIdx.x;
    if (b < 1024) {
        int e = b * 256 + threadIdx.x;          // [0, 2E)
        if (e < N_EDGES) {
            int s = eib[e], d = eib[N_EDGES + e];
            int pos = atomicAdd(&((int*)(ws + WS_HISTB))[d * SPREAD], 1);
            ((uint32_t*)(ws + WS_EDGEB))[pos] = (uint32_t)s;
        } else {
            int e2 = e - N_EDGES;
            int s = eif[e2], d = eif[N_EDGES + e2];
            int pos = atomicAdd(&((int*)(ws + WS_HISTF))[d * SPREAD], 1);
            ((uint32_t*)(ws + WS_EDGEF))[pos] = (uint32_t)s;
        }
    } else if (b < 1024 + N_NODES) {
        int row = b - 1024;
        int t = threadIdx.x;
        const float4* F = (const float4*)bfeat + (size_t)row * (DB / 4);
        float4 a0 = F[2 * t];
        float4 a1 = F[2 * t + 1];
        float aa = a0.x * a0.x + a0.y * a0.y + a0.z * a0.z + a0.w * a0.w
                 + a1.x * a1.x + a1.y * a1.y + a1.z * a1.z + a1.w * a1.w;
        #pragma unroll
        for (int off = 32; off; off >>= 1) aa += __shfl_xor(aa, off);
        if ((t & 63) == 0) redf[t >> 6] = aa;
        __syncthreads();
        float tot = redf[0] + redf[1] + redf[2] + redf[3];
        float inv = rsqrtf(tot + 1e-12f) * FP8_SCALE;
        uint2 o;
        o.x = pack4_fp8(a0.x * inv, a0.y * inv, a0.z * inv, a0.w * inv);
        o.y = pack4_fp8(a1.x * inv, a1.y * inv, a1.z * inv, a1.w * inv);
        ((uint2*)(ws + WS_FNB))[(size_t)row * 256 + t] = o;
    } else {
        int idx = (b - 1024 - N_NODES) * 4 + (threadIdx.x >> 6);
        int lane = threadIdx.x & 63;
        if (idx >= N_NODES) return;
        const float4* F = (const float4*)ffeat + (size_t)idx * (DF / 4);
        float4 a0 = F[2 * lane];
        float4 a1 = F[2 * lane + 1];
        float aa = a0.x * a0.x + a0.y * a0.y + a0.z * a0.z + a0.w * a0.w
                 + a1.x * a1.x + a1.y * a1.y + a1.z * a1.z + a1.w * a1.w;
        #pragma unroll
        for (int off = 32; off; off >>= 1) aa += __shfl_xor(aa, off);
        float inv = rsqrtf(aa + 1e-12f) * FP8_SCALE;
        uint2 o;
        o.x = pack4_fp8(a0.x * inv, a0.y * inv, a0.z * inv, a0.w * inv);
        o.y = pack4_fp8(a1.x * inv, a1.y * inv, a1.z * inv, a1.w * inv);
        ((uint2*)(ws + WS_FNF))[(size_t)idx * 64 + lane] = o;
    }
}

// ---- launch 7: one wave per DST node; dst row in regs; gather src rows.
// Epilogue (every node, even edge-less): dn = rsqrt(1+Σsim); wq = dn*p. ----
__global__ void k_edge_all(float* __restrict__ ws) {
    int wid  = (int)((blockIdx.x * blockDim.x + threadIdx.x) >> 6);
    int lane = threadIdx.x & 63;
    if (wid < N_NODES) {
        const int* start = (const int*)(ws + WS_STARTB);
        uint32_t* edges  = (uint32_t*)(ws + WS_EDGEB);
        int st = start[wid], en = start[wid + 1];
        float wdeg = 0.f;
        if (st < en) {
            const uint4* fn = (const uint4*)(ws + WS_FNB);
            const uint4* Dp = fn + (size_t)wid * 128;
            uint4 r0 = Dp[lane], r1 = Dp[lane + 64];
            float dstf[32];
            u32cvt(r0.x, dstf + 0);  u32cvt(r0.y, dstf + 4);
            u32cvt(r0.z, dstf + 8);  u32cvt(r0.w, dstf + 12);
            u32cvt(r1.x, dstf + 16); u32cvt(r1.y, dstf + 20);
            u32cvt(r1.z, dstf + 24); u32cvt(r1.w, dstf + 28);
            int i = st;
            for (; i + 3 < en; i += 4) {
                uint32_t w0 = edges[i], w1 = edges[i + 1], w2 = edges[i + 2], w3 = edges[i + 3];
                const uint4* A = fn + (size_t)(w0 & 0xFFFFu) * 128;
                const uint4* B = fn + (size_t)(w1 & 0xFFFFu) * 128;
                const uint4* C = fn + (size_t)(w2 & 0xFFFFu) * 128;
                const uint4* E = fn + (size_t)(w3 & 0xFFFFu) * 128;
                uint4 a0 = A[lane], a1 = A[lane + 64];
                uint4 b0 = B[lane], b1 = B[lane + 64];
                uint4 c0 = C[lane], c1 = C[lane + 64];
                uint4 e0 = E[lane], e1 = E[lane + 64];
                float s0 = 0.f, s1 = 0.f, s2 = 0.f, s3 = 0.f;
                s0 = dot16_fp8(a0, dstf, s0); s0 = dot16_fp8(a1, dstf + 16, s0);
                s1 = dot16_fp8(b0, dstf, s1); s1 = dot16_fp8(b1, dstf + 16, s1);
                s2 = dot16_fp8(c0, dstf, s2); s2 = dot16_fp8(c1, dstf + 16, s2);
                s3 = dot16_fp8(e0, dstf, s3); s3 = dot16_fp8(e1, dstf + 16, s3);
                #pragma unroll
                for (int off = 32; off; off >>= 1) {
                    s0 += __shfl_xor(s0, off); s1 += __shfl_xor(s1, off);
                    s2 += __shfl_xor(s2, off); s3 += __shfl_xor(s3, off);
                }
                if (lane == 0) {
                    float m0 = fmaxf(s0, 0.f) * FP8_DESCALE;
                    float m1 = fmaxf(s1, 0.f) * FP8_DESCALE;
                    float m2 = fmaxf(s2, 0.f) * FP8_DESCALE;
                    float m3 = fmaxf(s3, 0.f) * FP8_DESCALE;
                    edges[i]     = (w0 & 0xFFFFu) | ((uint32_t)f2h_bits(m0) << 16);
                    edges[i + 1] = (w1 & 0xFFFFu) | ((uint32_t)f2h_bits(m1) << 16);
                    edges[i + 2] = (w2 & 0xFFFFu) | ((uint32_t)f2h_bits(m2) << 16);
                    edges[i + 3] = (w3 & 0xFFFFu) | ((uint32_t)f2h_bits(m3) << 16);
                    wdeg += m0 + m1 + m2 + m3;
                }
            }
            for (; i < en; i++) {
                uint32_t w0 = edges[i];
                const uint4* A = fn + (size_t)(w0 & 0xFFFFu) * 128;
                uint4 a0 = A[lane], a1 = A[lane + 64];
                float s0 = 0.f;
                s0 = dot16_fp8(a0, dstf, s0); s0 = dot16_fp8(a1, dstf + 16, s0);
                #pragma unroll
                for (int off = 32; off; off >>= 1) s0 += __shfl_xor(s0, off);
                if (lane == 0) {
                    float m0 = fmaxf(s0, 0.f) * FP8_DESCALE;
                    edges[i] = (w0 & 0xFFFFu) | ((uint32_t)f2h_bits(m0) << 16);
                    wdeg += m0;
                }
            }
        }
        if (lane == 0) {
            float dn = rsqrtf(fmaxf(1.f + wdeg, 1e-6f));
            ws[WS_DNB + wid] = dn;
            uint32_t pme = ((const uint32_t*)(ws + WS_PBF))[wid];
            ws[WS_WQB + wid] = dn * h_bits2f((uint16_t)(pme & 0xFFFFu));
        }
    } else {
        int nid = wid - N_NODES;
        if (nid >= N_NODES) return;
        const int* start = (const int*)(ws + WS_STARTF);
        uint32_t* edges  = (uint32_t*)(ws + WS_EDGEF);
        int st = start[nid], en = start[nid + 1];
        float wdeg = 0.f;
        if (st < en) {
            const uint2* fn = (const uint2*)(ws + WS_FNF);
            uint2 sv = fn[(size_t)nid * 64 + lane];
            float dstf[8];
            u32cvt(sv.x, dstf); u32cvt(sv.y, dstf + 4);
            int i = st;
            for (; i + 3 < en; i += 4) {
                uint32_t w0 = edges[i], w1 = edges[i + 1], w2 = edges[i + 2], w3 = edges[i + 3];
                uint2 r0 = fn[(size_t)(w0 & 0xFFFFu) * 64 + lane];
                uint2 r1 = fn[(size_t)(w1 & 0xFFFFu) * 64 + lane];
                uint2 r2 = fn[(size_t)(w2 & 0xFFFFu) * 64 + lane];
                uint2 r3 = fn[(size_t)(w3 & 0xFFFFu) * 64 + lane];
                float c0 = u32dot(r0.y, dstf + 4, u32dot(r0.x, dstf, 0.f));
                float c1 = u32dot(r1.y, dstf + 4, u32dot(r1.x, dstf, 0.f));
                float c2 = u32dot(r2.y, dstf + 4, u32dot(r2.x, dstf, 0.f));
                float c3 = u32dot(r3.y, dstf + 4, u32dot(r3.x, dstf, 0.f));
                #pragma unroll
                for (int off = 32; off; off >>= 1) {
                    c0 += __shfl_xor(c0, off); c1 += __shfl_xor(c1, off);
                    c2 += __shfl_xor(c2, off); c3 += __shfl_xor(c3, off);
                }
                if (lane == 0) {
                    float m0 = fmaxf(c0, 0.f) * FP8_DESCALE;
                    float m1 = fmaxf(c1, 0.f) * FP8_DESCALE;
                    float m2 = fmaxf(c2, 0.f) * FP8_DESCALE;
                    float m3 = fmaxf(c3, 0.f) * FP8_DESCALE;
                    edges[i]     = (w0 & 0xFFFFu) | ((uint32_t)f2h_bits(m0) << 16);
                    edges[i + 1] = (w1 & 0xFFFFu) | ((uint32_t)f2h_bits(m1) << 16);
                    edges[i + 2] = (w2 & 0xFFFFu) | ((uint32_t)f2h_bits(m2) << 16);
                    edges[i + 3] = (w3 & 0xFFFFu) | ((uint32_t)f2h_bits(m3) << 16);
                    wdeg += m0 + m1 + m2 + m3;
                }
            }
            for (; i < en; i++) {
                uint32_t w0 = edges[i];
                uint2 r0 = fn[(size_t)(w0 & 0xFFFFu) * 64 + lane];
                float c0 = u32dot(r0.y, dstf + 4, u32dot(r0.x, dstf, 0.f));
                #pragma unroll
                for (int off = 32; off; off >>= 1) c0 += __shfl_xor(c0, off);
                if (lane == 0) {
                    float m0 = fmaxf(c0, 0.f) * FP8_DESCALE;
                    edges[i] = (w0 & 0xFFFFu) | ((uint32_t)f2h_bits(m0) << 16);
                    wdeg += m0;
                }
            }
        }
        if (lane == 0) {
            float dn = rsqrtf(fmaxf(1.f + wdeg, 1e-6f));
            ws[WS_DNF + nid] = dn;
            uint32_t pme = ((const uint32_t*)(ws + WS_PBF))[nid];
            ws[WS_WQF + nid] = dn * h_bits2f((uint16_t)(pme >> 16));
        }
    }
}

// ---- launch 8: thread-per-(dst,graph) pull over wq; halves join via LDS ----
__global__ void k_out(float* __restrict__ out, const float* __restrict__ ws) {
    __shared__ float part[128];
    int half = threadIdx.x >> 7;              // wave-uniform (waves 0,1 vs 2,3)
    int li   = threadIdx.x & 127;
    int i    = blockIdx.x * 128 + li;
    int g = half;
    const int* st       = (const int*)(ws + (g ? WS_STARTF : WS_STARTB));
    const uint32_t* eg  = (const uint32_t*)(ws + (g ? WS_EDGEF : WS_EDGEB));
    const float* wq     = ws + (g ? WS_WQF : WS_WQB);
    float sum = 0.f;
    int e0 = st[i], e1 = st[i + 1];
    for (int e = e0; e < e1; e++) {
        uint32_t w = eg[e];
        float sm = h_bits2f((uint16_t)(w >> 16));
        if (sm > 0.f) sum += sm * wq[w & 0xFFFFu];
    }
    float dn = ws[(g ? WS_DNF : WS_DNB) + i];
    uint32_t pme = ((const uint32_t*)(ws + WS_PBF))[i];
    float pv = h_bits2f(g ? (uint16_t)(pme >> 16) : (uint16_t)(pme & 0xFFFFu));
    float contrib = dn * dn * pv + dn * sum;
    if (half == 1) part[li] = contrib;
    __syncthreads();
    if (half == 0) out[i] = ws[WS_ACC + i] + contrib + part[li];
}

extern "C" void kernel_launch(void* const* d_in, const int* in_sizes, int n_in,
                              void* d_out, int out_size, void* d_ws, size_t ws_size,
                              hipStream_t stream) {
    const float* x     = (const float*)d_in[0];
    const float* bfeat = (const float*)d_in[1];
    const float* ffeat = (const float*)d_in[2];
    const int*   eib   = (const int*)d_in[3];
    const int*   eif   = (const int*)d_in[4];
    const float* w1    = (const float*)d_in[5];
    const float* b1    = (const float*)d_in[6];
    const float* gam   = (const float*)d_in[7];
    const float* bet   = (const float*)d_in[8];
    const float* pa    = (const float*)d_in[9];
    const float* w2    = (const float*)d_in[10];
    const float* b2    = (const float*)d_in[11];
    const float* w0w   = (const float*)d_in[12];
    const float* w0b   = (const float*)d_in[13];
    const float* gbw   = (const float*)d_in[14];
    const float* gbb   = (const float*)d_in[15];
    const float* gfw   = (const float*)d_in[16];
    const float* gfb   = (const float*)d_in[17];
    const float* wbw   = (const float*)d_in[18];
    const float* wbb   = (const float*)d_in[19];
    const float* wfw   = (const float*)d_in[20];
    const float* wfb   = (const float*)d_in[21];

    float* ws  = (float*)d_ws;
    float* out = (float*)d_out;

    k_pre<<<dim3(64 + 2 * N_NODES * SPREAD / 256), dim3(256), 0, stream>>>(x, ws);
    k_hist<<<dim3(1024), dim3(256), 0, stream>>>(eib, eif, ws);
    k_scanA<<<dim3(129), dim3(256), 0, stream>>>(w1, b1, gam, bet, w2, b2, w0w, w0b,
                                                 gbw, gbb, gfw, gfb, wbw, wbb, wfw, wfb, ws);
    k_scanB<<<dim3(1), dim3(256), 0, stream>>>(ws);
    k_scanC<<<dim3(192), dim3(256), 0, stream>>>(x, pa, ws);
    k_sortnorm<<<dim3(1024 + N_NODES + N_NODES / 4), dim3(256), 0, stream>>>(eib, eif, bfeat, ffeat, ws);
    k_edge_all<<<dim3(2 * N_NODES / 4), dim3(256), 0, stream>>>(ws);
    k_out<<<dim3(N_NODES / 128), dim3(256), 0, stream>>>(out, ws);
}